// Round 6
// baseline (74.460 us; speedup 1.0000x reference)
//
#include <hip/hip_runtime.h>
#include <hip/hip_bf16.h>
#include <math.h>

#define BSZ   4096
#define F     26
#define VOC   100000
#define D     64
#define AD    64
#define ND    13
#define FEA   77
#define NPAIR 325
#define NPAD  336    // 21 M-tiles of 16
#define MT    21
#define EP    68     // e row stride in floats
#define H1    256
#define H2    128
#define H3    64
#define EPSF  1e-5f
#define MROW  8      // k_mlp rows per block

typedef __attribute__((ext_vector_type(8))) short short8;
typedef __attribute__((ext_vector_type(4))) float f32x4;

union FragU { short8 s; unsigned int u[4]; };

__device__ __forceinline__ unsigned int pk2bf(float a, float b) {
  __hip_bfloat162 h = __float22bfloat162_rn(make_float2(a, b));  // v_cvt_pk_bf16_f32
  return *reinterpret_cast<unsigned int*>(&h);
}
__device__ __forceinline__ unsigned short f2bf(float f) {
  unsigned int u = __float_as_uint(f);
  u += 0x7fffu + ((u >> 16) & 1u);
  return (unsigned short)(u >> 16);
}
// VALU-pipe cross-lane add via DPP
template<int CTRL>
__device__ __forceinline__ float dpp_add(float x) {
  int xi = __builtin_bit_cast(int, x);
  int yi = __builtin_amdgcn_update_dpp(xi, xi, CTRL, 0xf, 0xf, false);
  return x + __builtin_bit_cast(float, yi);
}
// full 16-lane-row sum (all lanes get total): xor1, xor2, ror4, ror8
__device__ __forceinline__ float row16_sum(float x) {
  x = dpp_add<0xB1>(x);
  x = dpp_add<0x4E>(x);
  x = dpp_add<0x124>(x);
  x = dpp_add<0x128>(x);
  return x;
}

// ------- K1: attention. One WAVE per row; fused score+softmax+PV. ----------
__global__ __launch_bounds__(256, 4) void k_attn(
    const int* __restrict__ sx, const float* __restrict__ dx,
    const float* __restrict__ emb, const float* __restrict__ attW,
    const float* __restrict__ attb, const float* __restrict__ attdW,
    const float* __restrict__ attdb, float* __restrict__ x)
{
  __shared__ __align__(16) float e_all[4][27 * EP];   // row 26 = zeros
  __shared__ unsigned short pt[NPAD];

  const int t    = threadIdx.x;
  const int lane = t & 63;
  const int wv   = t >> 6;
  const int b    = blockIdx.x * 4 + wv;

  // pair table (f1 | f2<<8); pads -> zero-row 26
  for (int p = t; p < NPAD; p += 256) {
    int f1 = 26, f2 = 26;
    if (p < NPAIR) {
      int i = 0, rem = p;
      while (rem >= F - 1 - i) { rem -= F - 1 - i; ++i; }
      f1 = i; f2 = i + 1 + rem;
    }
    pt[p] = (unsigned short)(f1 | (f2 << 8));
  }

  float* e_w = e_all[wv];

  // gather: all index loads, then all emb loads, then all LDS stores (ILP)
  {
    int rowsv[7]; float4 vv[7];
    #pragma unroll
    for (int i = 0; i < 7; ++i) {
      int k = lane + 64 * i, f = k >> 4;
      rowsv[i] = (f < F) ? sx[b * F + f] : 0;
    }
    #pragma unroll
    for (int i = 0; i < 7; ++i) {
      int k = lane + 64 * i, f = k >> 4, q = k & 15;
      float4 v = {0.f, 0.f, 0.f, 0.f};
      if (f < F) v = *(const float4*)&emb[((size_t)f * VOC + rowsv[i]) * D + q * 4];
      vv[i] = v;
    }
    #pragma unroll
    for (int i = 0; i < 7; ++i) {
      int k = lane + 64 * i, f = k >> 4, q = k & 15;
      if (f < 27) *(float4*)&e_w[f * EP + q * 4] = vv[i];
    }
  }

  // B fragments (attW columns) + biases — global, L1/L2-resident
  short8 bfrag[2][4];
  float bj[4], dwj[4];
  {
    const int kb = (lane >> 4) * 8;
    const int cl = lane & 15;
    #pragma unroll
    for (int kk = 0; kk < 2; ++kk)
      #pragma unroll
      for (int n = 0; n < 4; ++n)
        #pragma unroll
        for (int j = 0; j < 8; ++j) {
          int k = kk * 32 + kb + j;
          bfrag[kk][n][j] = (short)f2bf(attW[k * AD + n * 16 + cl]);
        }
    #pragma unroll
    for (int n = 0; n < 4; ++n) {
      bj[n]  = attb[n * 16 + cl];
      dwj[n] = attdW[n * 16 + cl];
    }
  }
  const float db0 = attdb[0];

  __syncthreads();   // pt table only (e_w is wave-private)

  const int row16  = lane & 15;
  const int kgrp   = lane >> 4;
  const int kgrp4  = kgrp * 4;
  const int k0     = kgrp * 8;
  const int selsrc = ((row16 >> 2) << 4) | row16;  // lane holding my pair's score

  float pacc_a[8] = {0,0,0,0,0,0,0,0};   // att_out partial, d = kgrp*8 + j
  float pacc_b[8] = {0,0,0,0,0,0,0,0};   // d = 32 + kgrp*8 + j
  float m_run = -3.0e38f, l_lane = 0.f;

  for (int m = 0; m < MT; ++m) {
    const int prow = m * 16 + row16;           // this lane's A-row (pair)
    const unsigned short pp = pt[prow];
    const float* r1 = &e_w[(pp & 0xff) * EP];
    const float* r2 = &e_w[(pp >> 8) * EP];
    float4 x0 = *(const float4*)&r1[k0];
    float4 x1 = *(const float4*)&r1[k0 + 4];
    float4 y0 = *(const float4*)&r2[k0];
    float4 y1 = *(const float4*)&r2[k0 + 4];
    float4 x2 = *(const float4*)&r1[32 + k0];
    float4 x3 = *(const float4*)&r1[32 + k0 + 4];
    float4 y2 = *(const float4*)&r2[32 + k0];
    float4 y3 = *(const float4*)&r2[32 + k0 + 4];
    float ba[8] = {x0.x*y0.x, x0.y*y0.y, x0.z*y0.z, x0.w*y0.w,
                   x1.x*y1.x, x1.y*y1.y, x1.z*y1.z, x1.w*y1.w};
    float bb[8] = {x2.x*y2.x, x2.y*y2.y, x2.z*y2.z, x2.w*y2.w,
                   x3.x*y3.x, x3.y*y3.y, x3.z*y3.z, x3.w*y3.w};
    FragU a0, a1;
    a0.u[0] = pk2bf(ba[0], ba[1]); a0.u[1] = pk2bf(ba[2], ba[3]);
    a0.u[2] = pk2bf(ba[4], ba[5]); a0.u[3] = pk2bf(ba[6], ba[7]);
    a1.u[0] = pk2bf(bb[0], bb[1]); a1.u[1] = pk2bf(bb[2], bb[3]);
    a1.u[2] = pk2bf(bb[4], bb[5]); a1.u[3] = pk2bf(bb[6], bb[7]);

    f32x4 acc[4];
    #pragma unroll
    for (int n = 0; n < 4; ++n) {
      f32x4 z = {0.f, 0.f, 0.f, 0.f};
      acc[n] = __builtin_amdgcn_mfma_f32_16x16x32_bf16(a0.s, bfrag[0][n], z, 0, 0, 0);
      acc[n] = __builtin_amdgcn_mfma_f32_16x16x32_bf16(a1.s, bfrag[1][n], acc[n], 0, 0, 0);
    }
    // score for pair kgrp*4+r, known to all 16 lanes of this group
    float v4[4];
    #pragma unroll
    for (int r = 0; r < 4; ++r) {
      float val = 0.f;
      #pragma unroll
      for (int n = 0; n < 4; ++n)
        val += fmaxf(acc[n][r] + bj[n], 0.f) * dwj[n];
      v4[r] = row16_sum(val) + db0;
    }
    // redistribute: this lane's own pair score (pair = prow)
    float sel = v4[0];
    sel = ((row16 & 3) == 1) ? v4[1] : sel;
    sel = ((row16 & 3) == 2) ? v4[2] : sel;
    sel = ((row16 & 3) == 3) ? v4[3] : sel;
    const float s_p = __shfl(sel, selsrc);
    // tile max over valid pairs (wave-uniform)
    float lm = -3.0e38f;
    #pragma unroll
    for (int r = 0; r < 4; ++r) {
      int p = m * 16 + kgrp4 + r;
      if (p < NPAIR) lm = fmaxf(lm, v4[r]);
    }
    lm = fmaxf(lm, __shfl_xor(lm, 16));
    lm = fmaxf(lm, __shfl_xor(lm, 32));
    // online rescale
    if (lm > m_run) {
      const float scl = __expf(m_run - lm);   // first tile: exp(-huge) = 0
      l_lane *= scl;
      #pragma unroll
      for (int j = 0; j < 8; ++j) { pacc_a[j] *= scl; pacc_b[j] *= scl; }
      m_run = lm;
    }
    const float w = (prow < NPAIR) ? __expf(s_p - m_run) : 0.f;
    l_lane += w;
    #pragma unroll
    for (int j = 0; j < 8; ++j) {
      pacc_a[j] = fmaf(w, ba[j], pacc_a[j]);
      pacc_b[j] = fmaf(w, bb[j], pacc_b[j]);
    }
  }

  // final: reduce over the 16 row16 lanes, normalize, store
  const float l_tot = row16_sum(l_lane);
  const float invZ = 1.f / l_tot;
  #pragma unroll
  for (int j = 0; j < 8; ++j) {
    pacc_a[j] = row16_sum(pacc_a[j]);
    pacc_b[j] = row16_sum(pacc_b[j]);
  }
  if (row16 == 0) {                      // lanes 0,16,32,48
    float* xo = &x[(size_t)b * FEA + kgrp * 8];
    #pragma unroll
    for (int j = 0; j < 8; ++j) xo[j] = pacc_a[j] * invZ;
    float* xo2 = &x[(size_t)b * FEA + 32 + kgrp * 8];
    #pragma unroll
    for (int j = 0; j < 8; ++j) xo2[j] = pacc_b[j] * invZ;
  }
  if (lane >= 8 && lane < 8 + ND) {
    x[(size_t)b * FEA + D + (lane - 8)] = dx[b * ND + (lane - 8)];
  }
}

// ---------------- K2: batchnorm stats (block per feature) ----------------
__global__ __launch_bounds__(256) void k_bnstats(
    const float* __restrict__ x, const float* __restrict__ gamma,
    const float* __restrict__ beta, float* __restrict__ scale,
    float* __restrict__ shift)
{
  const int f = blockIdx.x;
  const int t = threadIdx.x;
  const int lane = t & 63;
  const int wv = t >> 6;
  double s = 0.0, s2 = 0.0;
  for (int b = t; b < BSZ; b += 256) {
    float v = x[(size_t)b * FEA + f];
    s += v;
    s2 += (double)v * v;
  }
  #pragma unroll
  for (int off = 32; off; off >>= 1) {
    s += __shfl_xor(s, off);
    s2 += __shfl_xor(s2, off);
  }
  __shared__ double rs[4], rs2[4];
  if (lane == 0) { rs[wv] = s; rs2[wv] = s2; }
  __syncthreads();
  if (t == 0) {
    double S = 0.0, S2 = 0.0;
    #pragma unroll
    for (int i = 0; i < 4; ++i) { S += rs[i]; S2 += rs2[i]; }
    double mu = S / BSZ;
    double var = S2 / BSZ - mu * mu;
    float g = gamma[f];
    float scl = (float)((double)g / sqrt(var + (double)EPSF));
    scale[f] = scl;
    shift[f] = beta[f] - (float)mu * scl;
  }
}

// ---------------- K3: MLP (8 rows per block, 512 blocks) ----------------
__global__ __launch_bounds__(256) void k_mlp(
    const float* __restrict__ x,
    const float* __restrict__ scale, const float* __restrict__ shift,
    const float* __restrict__ w1, const float* __restrict__ b1,
    const float* __restrict__ w2, const float* __restrict__ b2,
    const float* __restrict__ w3, const float* __restrict__ b3,
    const float* __restrict__ wf, const float* __restrict__ bf,
    float* __restrict__ out)
{
  __shared__ float xn[MROW][80];
  __shared__ float h1s[MROW][H1];
  __shared__ float h2s[MROW][H2];
  __shared__ float h3s[MROW][H3];
  const int t = threadIdx.x;
  const int b0 = blockIdx.x * MROW;

  for (int k = t; k < MROW * FEA; k += 256) {
    int r = k / FEA, f = k % FEA;
    xn[r][f] = x[(size_t)(b0 + r) * FEA + f] * scale[f] + shift[f];
  }
  __syncthreads();

  {
    float acc[MROW];
    const float bb = b1[t];
    #pragma unroll
    for (int r = 0; r < MROW; ++r) acc[r] = bb;
    for (int d = 0; d < FEA; ++d) {
      float wv = w1[d * H1 + t];
      #pragma unroll
      for (int r = 0; r < MROW; ++r) acc[r] = fmaf(xn[r][d], wv, acc[r]);
    }
    #pragma unroll
    for (int r = 0; r < MROW; ++r) h1s[r][t] = fmaxf(acc[r], 0.f);
  }
  __syncthreads();

  {
    const int j = t & 127;
    const int rb = (t >> 7) * 4;
    float acc[4];
    const float bb = b2[j];
    #pragma unroll
    for (int r = 0; r < 4; ++r) acc[r] = bb;
    for (int k = 0; k < H1; ++k) {
      float wv = w2[k * H2 + j];
      #pragma unroll
      for (int r = 0; r < 4; ++r) acc[r] = fmaf(h1s[rb + r][k], wv, acc[r]);
    }
    #pragma unroll
    for (int r = 0; r < 4; ++r) h2s[rb + r][j] = fmaxf(acc[r], 0.f);
  }
  __syncthreads();

  {
    const int j = t & 63;
    const int rb = (t >> 6) * 2;
    float acc[2];
    const float bb = b3[j];
    #pragma unroll
    for (int r = 0; r < 2; ++r) acc[r] = bb;
    for (int k = 0; k < H2; ++k) {
      float wv = w3[k * H3 + j];
      #pragma unroll
      for (int r = 0; r < 2; ++r) acc[r] = fmaf(h2s[rb + r][k], wv, acc[r]);
    }
    #pragma unroll
    for (int r = 0; r < 2; ++r) h3s[rb + r][j] = fmaxf(acc[r], 0.f);
  }
  __syncthreads();

  if (t < MROW) {
    float acc = bf[0];
    for (int k = 0; k < H3; ++k) acc = fmaf(h3s[t][k], wf[k], acc);
    out[b0 + t] = 1.f / (1.f + __expf(-acc));
  }
}

extern "C" void kernel_launch(void* const* d_in, const int* in_sizes, int n_in,
                              void* d_out, int out_size, void* d_ws, size_t ws_size,
                              hipStream_t stream) {
  const int*   sx    = (const int*)  d_in[0];
  const float* dx    = (const float*)d_in[1];
  const float* emb   = (const float*)d_in[2];
  const float* attW  = (const float*)d_in[3];
  const float* attb  = (const float*)d_in[4];
  const float* attdW = (const float*)d_in[5];
  const float* attdb = (const float*)d_in[6];
  const float* gamma = (const float*)d_in[7];
  const float* beta  = (const float*)d_in[8];
  const float* w1    = (const float*)d_in[9];
  const float* b1    = (const float*)d_in[10];
  const float* w2    = (const float*)d_in[11];
  const float* b2    = (const float*)d_in[12];
  const float* w3    = (const float*)d_in[13];
  const float* b3    = (const float*)d_in[14];
  const float* wf    = (const float*)d_in[15];
  const float* bf    = (const float*)d_in[16];
  float* out = (float*)d_out;

  float* x     = (float*)d_ws;              // B*FEA
  float* scale = x + (size_t)BSZ * FEA;     // FEA
  float* shift = scale + FEA;               // FEA

  k_attn<<<BSZ / 4, 256, 0, stream>>>(sx, dx, emb, attW, attb, attdW, attdb, x);
  k_bnstats<<<FEA, 256, 0, stream>>>(x, gamma, beta, scale, shift);
  k_mlp<<<BSZ / MROW, 256, 0, stream>>>(x, scale, shift, w1, b1, w2, b2, w3, b3,
                                        wf, bf, out);
}